// Round 11
// baseline (338.449 us; speedup 1.0000x reference)
//
#include <hip/hip_runtime.h>
#include <hip/hip_bf16.h>
#include <math.h>

#define HW   4096
#define CCH  256
#define NE   8
#define HID  512
#define NTOK 65536
#define PADH 264   // Hs row pitch in BYTES (fp8): 8B-aligned rows, spread banks

typedef short s16x8 __attribute__((ext_vector_type(8)));
typedef float f32x4 __attribute__((ext_vector_type(4)));
typedef unsigned short u16x8 __attribute__((ext_vector_type(8)));
typedef unsigned short u16x4 __attribute__((ext_vector_type(4)));

// Fast exact-enough GELU: v * sigmoid(2u), u = 0.79788456*(v + 0.044715 v^3).
__device__ __forceinline__ float fast_gelu(float v) {
    float v2 = v * v;
    float s  = v * fmaf(0.10294324f, v2, 2.3022079f);
    float e  = exp2f(-s);
    return v * __builtin_amdgcn_rcpf(1.0f + e);
}

__device__ __forceinline__ float bfbits2f(unsigned short h) {
    return __uint_as_float(((unsigned)h) << 16);
}

__device__ __forceinline__ short f2bf_bits(float f) {
    __hip_bfloat16 b = __float2bfloat16(f);
    return *reinterpret_cast<short*>(&b);
}

__device__ __forceinline__ unsigned short f2bf_ubits(float f) {
    __hip_bfloat16 b = __float2bfloat16(f);
    return *reinterpret_cast<unsigned short*>(&b);
}

// ---- fp8 e4m3 (OCP) conversion via v_cvt_pk_fp8_f32 ----
__device__ __forceinline__ unsigned pk4_fp8(float a, float b, float c, float d) {
    int v = 0;
    v = __builtin_amdgcn_cvt_pk_fp8_f32(a, b, v, false);  // bytes 0,1
    v = __builtin_amdgcn_cvt_pk_fp8_f32(c, d, v, true);   // bytes 2,3
    return (unsigned)v;
}
__device__ __forceinline__ unsigned char f2fp8(float a) {
    return (unsigned char)(__builtin_amdgcn_cvt_pk_fp8_f32(a, a, 0, false) & 0xff);
}

// ---------------- K transpose+cast to FP8 for BOTH weights (+ meta zero) ----
// blocks [0,256): W1 (E,256,512)->(E,512,256) fp8; [256,512): W2 -> (E,256,512) fp8
__global__ __launch_bounds__(256) void k_transpose_both(
    const float* __restrict__ W1, const float* __restrict__ W2,
    unsigned char* __restrict__ w1t, unsigned char* __restrict__ w2t,
    int* __restrict__ meta)
{
    __shared__ float t[64][65];
    if (blockIdx.x == 0 && threadIdx.x < 16) meta[threadIdx.x] = 0;  // counts+cursors
    int bb = blockIdx.x;
    const float* in; unsigned char* out; int R, CC;
    if (bb < 256) { in = W1; out = w1t; R = 256; CC = 512; }
    else          { in = W2; out = w2t; R = 512; CC = 256; bb -= 256; }
    int tilesC = CC >> 6;
    int per = (R >> 6) * tilesC;
    int e = bb / per, tt = bb % per;
    int r0 = (tt / tilesC) << 6, c0 = (tt % tilesC) << 6;
    const float* ip = in + (size_t)e * R * CC;
    unsigned char* op = out + (size_t)e * R * CC;
    int lane = threadIdx.x & 63, g = threadIdx.x >> 6;
    for (int i = 0; i < 16; i++) {
        int r = i * 4 + g;
        t[r][lane] = ip[(size_t)(r0 + r) * CC + c0 + lane];
    }
    __syncthreads();
    for (int i = 0; i < 16; i++) {
        int r = i * 4 + g;
        op[(size_t)(c0 + r) * R + r0 + lane] = f2fp8(t[lane][r]);
    }
}

// ---------------- K0: router, 32-token tiles, fused reg-logits, fp8 tokens --
__global__ __launch_bounds__(256) void k_router(
    const float* __restrict__ x, const float* __restrict__ Wr, const float* __restrict__ br,
    unsigned char* __restrict__ tokens, int* __restrict__ pair, float2* __restrict__ wts,
    int* __restrict__ meta /* counts at [0..8) */)
{
    __shared__ float xt[CCH][33];      // 33.8 KB
    __shared__ float wrp[2304];        // Wr staged [c*8+e]; reused as plg
    __shared__ float lg[32][NE];
    __shared__ int lc[NE];
    int tid = threadIdx.x;
    int n0 = blockIdx.x * 32;
    int b = n0 >> 12, p0 = n0 & 4095;
    const float* xb = x + (size_t)b * CCH * HW + p0;
    for (int i = tid; i < CCH * NE; i += 256) wrp[i] = Wr[i];
    if (tid < NE) lc[tid] = 0;
    __syncthreads();
    int j = tid & 31, cg = tid >> 5;
    float pacc[8];
#pragma unroll
    for (int e = 0; e < 8; e++) pacc[e] = 0.f;
    for (int i = 0; i < 32; i++) {
        int c = cg + 8 * i;
        float xv = xb[(size_t)c * HW + j];
        xt[c][j] = xv;
        const float4* wp = (const float4*)(wrp + c * 8);
        float4 wa = wp[0], wb2 = wp[1];
        pacc[0] = fmaf(xv, wa.x, pacc[0]);
        pacc[1] = fmaf(xv, wa.y, pacc[1]);
        pacc[2] = fmaf(xv, wa.z, pacc[2]);
        pacc[3] = fmaf(xv, wa.w, pacc[3]);
        pacc[4] = fmaf(xv, wb2.x, pacc[4]);
        pacc[5] = fmaf(xv, wb2.y, pacc[5]);
        pacc[6] = fmaf(xv, wb2.z, pacc[6]);
        pacc[7] = fmaf(xv, wb2.w, pacc[7]);
    }
    __syncthreads();
    float* plg = wrp;
#pragma unroll
    for (int e = 0; e < 8; e++) plg[(cg * 32 + j) * 9 + e] = pacc[e];
    __syncthreads();
    {
        int jj = tid & 31, e = tid >> 5;
        float s = br[e];
#pragma unroll
        for (int g = 0; g < 8; g++) s += plg[(g * 32 + jj) * 9 + e];
        lg[jj][e] = s;
    }
    __syncthreads();
    if (tid < 32) {
        float v0 = -1e30f, v1 = -1e30f; int i0 = 0, i1 = 0;
        for (int e = 0; e < NE; e++) {
            float l = lg[tid][e];
            if (l > v0)      { v1 = v0; i1 = i0; v0 = l; i0 = e; }
            else if (l > v1) { v1 = l; i1 = e; }
        }
        float e1 = expf(v1 - v0);
        float s = 1.0f + e1;
        wts[n0 + tid] = make_float2(1.0f / s, e1 / s);
        pair[n0 + tid] = i0 | (i1 << 8);
        atomicAdd(&lc[i0], 1);
        atomicAdd(&lc[i1], 1);
    }
    __syncthreads();
    if (tid < NE && lc[tid] > 0) atomicAdd(&meta[tid], lc[tid]);
    // ---- token write (fp8): thread (j, cg) writes 4 x 8-byte chunks
#pragma unroll
    for (int i = 0; i < 4; i++) {
        int c0 = (cg + 8 * i) * 8;
        uint2 pk;
        pk.x = pk4_fp8(xt[c0 + 0][j], xt[c0 + 1][j], xt[c0 + 2][j], xt[c0 + 3][j]);
        pk.y = pk4_fp8(xt[c0 + 4][j], xt[c0 + 5][j], xt[c0 + 6][j], xt[c0 + 7][j]);
        *(uint2*)(tokens + (size_t)(n0 + j) * CCH + c0) = pk;
    }
}

// ---------------- K2: scatter tokens into per-expert lists (scan fused) -----
// meta: [0..8) counts, [8..16) cursors, [16..25) offsets, [25..34) tilestart, [34] total
// 64-token tiles (k_expert r0 = tile<<6).
__global__ __launch_bounds__(256) void k_scatter(
    const int* __restrict__ pair, const float2* __restrict__ wts,
    int* __restrict__ meta, int* __restrict__ assign_tok, float* __restrict__ assign_w,
    int2* __restrict__ tok_slots)
{
    __shared__ int lcount[NE];
    __shared__ int lbase[NE];
    __shared__ int soff[NE];
    int tid = threadIdx.x;
    int n = blockIdx.x * 256 + tid;
    if (tid < NE) lcount[tid] = 0;
    __syncthreads();
    int pr = pair[n];
    int e0 = pr & 0xff, e1 = (pr >> 8) & 0xff;
    int p0 = atomicAdd(&lcount[e0], 1);
    int p1 = atomicAdd(&lcount[e1], 1);
    __syncthreads();
    if (tid == 0) {
        int off = 0, toff = 0;
        for (int ee = 0; ee < NE; ee++) {
            soff[ee] = off;
            int c = meta[ee];
            if (blockIdx.x == 0) { meta[16 + ee] = off; meta[25 + ee] = toff; }
            off += c;
            toff += (c + 63) >> 6;
        }
        if (blockIdx.x == 0) { meta[24] = off; meta[33] = toff; meta[34] = toff; }
    }
    if (tid < NE) lbase[tid] = atomicAdd(&meta[8 + tid], lcount[tid]);
    __syncthreads();
    float2 w = wts[n];
    int s0 = soff[e0] + lbase[e0] + p0;
    int s1 = soff[e1] + lbase[e1] + p1;
    assign_tok[s0] = n; assign_w[s0] = w.x;
    assign_tok[s1] = n; assign_w[s1] = w.y;
    tok_slots[n] = make_int2(s0, s1);
}

// ---------------- K3: grouped fused MLP, fp8 (the hot kernel) ---------------
// R4-proven 64-token / 8-wave / 2-blocks-per-CU structure, weights+tokens+Hs
// in fp8 e4m3: weight stream 1.05GB -> 0.53GB at the measured-invariant
// ~6.1 TB/s service rate (stream-bound: R4 1.05GB/173us). MFMA via
// mfma_f32_16x16x32_fp8_fp8 (same shape/rate as bf16, i64 fragments).
// LDS: Af 16KB + Hs 16.5KB -> ~34KB; regs <=128 -> 2 blocks/CU retained.
__global__ __launch_bounds__(512, 4) void k_expert(
    const unsigned char* __restrict__ tokens,
    const unsigned char* __restrict__ w1t,   // (E, HID, C)  = W1^T fp8
    const unsigned char* __restrict__ w2t,   // (E, C, HID)  = W2^T fp8
    const float* __restrict__ b1, const float* __restrict__ b2,
    const int* __restrict__ meta,
    const int* __restrict__ assign_tok, const float* __restrict__ assign_w,
    __hip_bfloat16* __restrict__ ybuf)
{
    __shared__ __align__(16) unsigned char Af[64 * 256];   // 16 KB, frag-linear 8B units
    __shared__ __align__(16) unsigned char Hs[64 * PADH];  // 16.5 KB
    __shared__ float wrow[64];
    __shared__ int trow[64];

    int total = meta[34];
    int swz = (int)blockIdx.x;
    int bid = (swz & 7) * 257 + (swz >> 3);    // grid 2056 = 8*257, bijective
    if (bid >= total) return;
    int e = 0;
    while (e < 7 && bid >= meta[25 + e + 1]) e++;
    int tile = bid - meta[25 + e];
    int cnt = meta[e];
    int r0 = tile << 6;
    int abase = meta[16 + e] + r0;
    int nrows = cnt - r0; if (nrows > 64) nrows = 64;

    int tid = threadIdx.x;
    if (tid < 64) {
        if (tid < nrows) { trow[tid] = assign_tok[abase + tid]; wrow[tid] = assign_w[abase + tid]; }
        else             { trow[tid] = 0; wrow[tid] = 0.0f; }
    }
    __syncthreads();

    // ---- stage A tile (fp8 frag-linear: unit U = mt*512 + (kk*4+quad)*16 + l15,
    //      8 bytes each; lane-linear writes => no conflicts)
    {
        unsigned long long* dst = (unsigned long long*)Af;
#pragma unroll
        for (int j = 0; j < 4; j++) {
            int row = j * 16 + (tid & 15);
            int chunk = (tid >> 4) & 31;
            dst[j * 512 + tid] =
                ((const unsigned long long*)(tokens + (size_t)trow[row] * CCH))[chunk];
        }
    }

    int lane = tid & 63, wv = tid >> 6;      // wv in [0,8)
    int quad = lane >> 4, l15 = lane & 15;

    const unsigned char* w1e = w1t + (size_t)e * HID * CCH;
    const unsigned char* w2e = w2t + (size_t)e * CCH * HID;
    const float* b1e = b1 + e * HID;
    const float* b2e = b2 + e * CCH;

    const long* apb = (const long*)Af + quad * 16 + l15;   // + mt*512 + kk*64

    auto G1Q = [&](int h, int off) {
        return (const long*)(w1e + (size_t)(h * 256 + wv * 32 + off + l15) * CCH) + quad;
    };
    auto G2Q = [&](int h, int off) {
        return (const long*)(w2e + (size_t)(wv * 32 + off + l15) * HID + h * 256) + quad;
    };

    f32x4 oacc[4][2];
#pragma unroll
    for (int i = 0; i < 4; i++)
#pragma unroll
        for (int j = 0; j < 2; j++) oacc[i][j] = (f32x4){0.f, 0.f, 0.f, 0.f};

    // issue h=0 GEMM1 first B-frags and epilogue biases before the A barrier
    long bf0 = G1Q(0, 0)[0], bf1 = G1Q(0, 16)[0];
    float ob0 = b2e[wv * 32 + l15];
    float ob1 = b2e[wv * 32 + 16 + l15];

    __syncthreads();   // A tile visible (barrier drain also completes bf0/bf1)

#pragma unroll
    for (int h = 0; h < 2; h++) {
        const long* bq0 = G1Q(h, 0);
        const long* bq1 = G1Q(h, 16);

        f32x4 hacc[4][2];
#pragma unroll
        for (int i = 0; i < 4; i++)
#pragma unroll
            for (int j = 0; j < 2; j++) hacc[i][j] = (f32x4){0.f, 0.f, 0.f, 0.f};

        // ---- GEMM1: hacc[mt][nt] over K=256 (8 x K=32 fp8 MFMA)
#pragma unroll
        for (int kk = 0; kk < 8; kk++) {
            long bn0, bn1;
            if (kk < 7) { bn0 = bq0[(kk + 1) * 4]; bn1 = bq1[(kk + 1) * 4]; }
            long af[4];
#pragma unroll
            for (int mt = 0; mt < 4; mt++) af[mt] = apb[mt * 512 + kk * 64];
            __builtin_amdgcn_s_setprio(1);
#pragma unroll
            for (int mt = 0; mt < 4; mt++) {
                hacc[mt][0] = __builtin_amdgcn_mfma_f32_16x16x32_fp8_fp8(af[mt], bf0, hacc[mt][0], 0, 0, 0);
                hacc[mt][1] = __builtin_amdgcn_mfma_f32_16x16x32_fp8_fp8(af[mt], bf1, hacc[mt][1], 0, 0, 0);
            }
            __builtin_amdgcn_s_setprio(0);
            bf0 = bn0; bf1 = bn1;
        }

        // issue next-phase operands early (completed under GELU / barrier drain)
        const long* b2q0 = G2Q(h, 0);
        const long* b2q1 = G2Q(h, 16);
        long cf0 = b2q0[0], cf1 = b2q1[0];
        float biasA = b1e[h * 256 + wv * 32 + l15];
        float biasB = b1e[h * 256 + wv * 32 + 16 + l15];
        if (h == 0) { bf0 = G1Q(1, 0)[0]; bf1 = G1Q(1, 16)[0]; }

        // Barrier needed only at h=1 (Hs reuse); h=0's Hs untouched since start.
        if (h == 1) __syncthreads();

        // ---- bias + fast GELU -> Hs fp8 (local col cl in [0,256))
#pragma unroll
        for (int nt = 0; nt < 2; nt++) {
            int cl = wv * 32 + nt * 16 + l15;
            float bias = nt ? biasB : biasA;
#pragma unroll
            for (int mt = 0; mt < 4; mt++)
#pragma unroll
                for (int r = 0; r < 4; r++) {
                    int row = mt * 16 + quad * 4 + r;
                    float v = hacc[mt][nt][r] + bias;
                    Hs[row * PADH + cl] = f2fp8(fast_gelu(v));
                }
        }
        __syncthreads();   // Hs complete before GEMM2 reads

        // ---- GEMM2: A = Hs rows (LDS fp8), B = W2^T rows (global/L2), K=256
#pragma unroll
        for (int kk = 0; kk < 8; kk++) {
            long cn0, cn1;
            if (kk < 7) { cn0 = b2q0[(kk + 1) * 4]; cn1 = b2q1[(kk + 1) * 4]; }
            long hf[4];
#pragma unroll
            for (int mt = 0; mt < 4; mt++)
                hf[mt] = *(const long*)(Hs + (size_t)(mt * 16 + l15) * PADH + kk * 32 + quad * 8);
            __builtin_amdgcn_s_setprio(1);
#pragma unroll
            for (int mt = 0; mt < 4; mt++) {
                oacc[mt][0] = __builtin_amdgcn_mfma_f32_16x16x32_fp8_fp8(hf[mt], cf0, oacc[mt][0], 0, 0, 0);
                oacc[mt][1] = __builtin_amdgcn_mfma_f32_16x16x32_fp8_fp8(hf[mt], cf1, oacc[mt][1], 0, 0, 0);
            }
            __builtin_amdgcn_s_setprio(0);
            cf0 = cn0; cf1 = cn1;
        }
        // no barrier at h=0 end: the h=1 pre-GELU barrier protects Hs
    }

    // ---- epilogue: (acc + b2) * route_weight -> ybuf[slot][c] bf16
#pragma unroll
    for (int nt = 0; nt < 2; nt++) {
        int cc = wv * 32 + nt * 16 + l15;
        float bias = nt ? ob1 : ob0;
#pragma unroll
        for (int mt = 0; mt < 4; mt++) {
#pragma unroll
            for (int r = 0; r < 4; r++) {
                int row = mt * 16 + quad * 4 + r;
                if (row < nrows) {
                    float v = (oacc[mt][nt][r] + bias) * wrow[row];
                    ybuf[(size_t)(abase + row) * CCH + cc] = __float2bfloat16(v);
                }
            }
        }
    }
}

// ---------------- K4: combine two expert outputs, transpose back, residual --
__global__ __launch_bounds__(256) void k_combine(
    const float* __restrict__ x, const __hip_bfloat16* __restrict__ ybuf,
    const int2* __restrict__ tok_slots, const float* __restrict__ scale,
    float* __restrict__ out)
{
    __shared__ __align__(16) unsigned short moe[CCH][36];   // 18 KB
    __shared__ int2 slots[32];
    int tid = threadIdx.x;
    int n0 = blockIdx.x * 32;
    if (tid < 32) slots[tid] = tok_slots[n0 + tid];
    __syncthreads();
    {
        int r = tid & 31, g0 = tid >> 5;
#pragma unroll
        for (int it = 0; it < 2; it++) {
            int g = g0 + 8 * it;
            int2 s = slots[r];
            const u16x8* px = (const u16x8*)(ybuf + (size_t)s.x * CCH + 16 * g);
            const u16x8* py = (const u16x8*)(ybuf + (size_t)s.y * CCH + 16 * g);
            u16x8 ax0 = px[0], ax1 = px[1], ay0 = py[0], ay1 = py[1];
#pragma unroll
            for (int k = 0; k < 8; k++) {
                moe[16 * g + k][r]     = f2bf_ubits(bfbits2f(ax0[k]) + bfbits2f(ay0[k]));
                moe[16 * g + 8 + k][r] = f2bf_ubits(bfbits2f(ax1[k]) + bfbits2f(ay1[k]));
            }
        }
    }
    __syncthreads();
    float sc = scale[0];
    int b = n0 >> 12, p0 = n0 & 4095;
    const float* xb = x + (size_t)b * CCH * HW + p0;
    float* ob = out + (size_t)b * CCH * HW + p0;
    int j = tid & 7, cbase = tid >> 3;
#pragma unroll
    for (int i = 0; i < 8; i++) {
        int c = cbase + 32 * i;
        float4 xv = *(const float4*)(xb + (size_t)c * HW + 4 * j);
        u16x4 mv = *(const u16x4*)&moe[c][4 * j];
        float4 o;
        o.x = xv.x + sc * bfbits2f(mv[0]);
        o.y = xv.y + sc * bfbits2f(mv[1]);
        o.z = xv.z + sc * bfbits2f(mv[2]);
        o.w = xv.w + sc * bfbits2f(mv[3]);
        *(float4*)(ob + (size_t)c * HW + 4 * j) = o;
    }
}

// ---------------- launch ----------------------------------------------------
extern "C" void kernel_launch(void* const* d_in, const int* in_sizes, int n_in,
                              void* d_out, int out_size, void* d_ws, size_t ws_size,
                              hipStream_t stream)
{
    const float* x     = (const float*)d_in[0];
    const float* Wr    = (const float*)d_in[1];
    const float* br    = (const float*)d_in[2];
    const float* W1    = (const float*)d_in[3];
    const float* b1    = (const float*)d_in[4];
    const float* W2    = (const float*)d_in[5];
    const float* b2    = (const float*)d_in[6];
    const float* scale = (const float*)d_in[7];
    float* out = (float*)d_out;

    char* ws = (char*)d_ws;
    unsigned char*  tokens = (unsigned char*)(ws);                  // 16 MB used (fp8)
    unsigned char*  w1t    = (unsigned char*)(ws + 33554432);       //  1 MB used (fp8)
    unsigned char*  w2t    = (unsigned char*)(ws + 35651584);       //  1 MB used (fp8)
    __hip_bfloat16* ybuf   = (__hip_bfloat16*)(ws + 37748736);      // 64 MB
    int*    assign_tok = (int*)   (ws + 104857600);                 //    524,288 B
    float*  assign_w   = (float*) (ws + 105381888);                 //    524,288 B
    int2*   tok_slots  = (int2*)  (ws + 105906176);                 //    524,288 B
    int*    pair       = (int*)   (ws + 106430464);                 //    262,144 B
    float2* wts        = (float2*)(ws + 106692608);                 //    524,288 B
    int*    meta       = (int*)   (ws + 107216896);                 //        256 B

    k_transpose_both<<<512, 256, 0, stream>>>(W1, W2, w1t, w2t, meta);
    k_router<<<2048, 256, 0, stream>>>(x, Wr, br, tokens, pair, wts, meta);
    k_scatter<<<256, 256, 0, stream>>>(pair, wts, meta, assign_tok, assign_w, tok_slots);
    k_expert<<<2056, 512, 0, stream>>>(tokens, w1t, w2t, b1, b2, meta,
                                       assign_tok, assign_w, ybuf);
    k_combine<<<2048, 256, 0, stream>>>(x, ybuf, tok_slots, scale, out);
}